// Round 12
// baseline (118.155 us; speedup 1.0000x reference)
//
#include <hip/hip_runtime.h>
#include <hip/hip_bf16.h>

#define B_ 2
#define P_ 100000
#define CIN_ 23
#define C_ 64
#define H_ 512
#define W_ 512
#define S_ (H_*W_)       // 262144
#define NPT_ (B_*P_)     // 200000
#define NVOX_ (B_*S_)    // 524288

typedef __attribute__((ext_vector_type(8))) short short8;
typedef __attribute__((ext_vector_type(4))) float f32x4;
typedef __attribute__((ext_vector_type(4))) int i32x4;

__device__ inline unsigned short f2bf(float f) {
    union { __hip_bfloat16 h; unsigned short u; } cv;
    cv.h = __float2bfloat16(f);
    return cv.u;
}
__device__ inline float bf2f(unsigned short u) {
    union { unsigned int i; float f; } cv;
    cv.i = ((unsigned int)u) << 16;
    return cv.f;
}

// ---------------- Stage 1: histogram ----------------
__global__ __launch_bounds__(256) void k_hist(
    const int* __restrict__ indices,
    const int* __restrict__ paddings,
    int* __restrict__ cnt)
{
    int pt = blockIdx.x * 256 + threadIdx.x;
    if (pt >= NPT_) return;
    if (paddings[pt] != 0) return;
    int v = (pt / P_) * S_ + indices[pt];
    atomicAdd(&cnt[v], 1);
}

// ---------------- Stage 2: exclusive-scan offsets + (block 512) param prep ----------
__global__ __launch_bounds__(256) void k_offsets(
    const int* __restrict__ cnt,
    int* __restrict__ off,
    int* __restrict__ cur,
    int* __restrict__ gcursor,
    const float* __restrict__ conv_w,
    const float* __restrict__ w_pn,
    const float* __restrict__ g1, const float* __restrict__ b1,
    const float* __restrict__ m1, const float* __restrict__ v1,
    const float* __restrict__ g2, const float* __restrict__ b2,
    const float* __restrict__ m2, const float* __restrict__ v2,
    unsigned short* __restrict__ cwb,   // [8][64][8] bf16 conv-W fragments
    unsigned short* __restrict__ wpb,   // [4][64][8] bf16 w_pn fragments
    float* __restrict__ s1v, float* __restrict__ o1v,
    float* __restrict__ scv, float* __restrict__ shv)
{
    if (blockIdx.x >= 512) {            // ---- prep block ----
        int t = threadIdx.x;
        if (t < 64) {
            float s = g1[t] * rsqrtf(v1[t] + 1e-5f);
            s1v[t] = s;
            o1v[t] = b1[t] - m1[t] * s;
            float s2 = g2[t] * rsqrtf(v2[t] + 1e-3f);
            scv[t] = s2;
            shv[t] = b2[t] - m2[t] * s2;
        }
        #pragma unroll
        for (int e = 0; e < 16; ++e) {
            int idx  = t * 16 + e;              // 0..4095
            int f    = idx >> 9;                // 0..7
            int lane = (idx >> 3) & 63;
            int j    = idx & 7;
            int tq = f >> 1, ks = f & 1;
            int row = lane & 15, grp = lane >> 4;
            cwb[idx] = f2bf(conv_w[(tq * 16 + row) * 64 + ks * 32 + grp * 8 + j]);
        }
        #pragma unroll
        for (int e = 0; e < 8; ++e) {
            int idx  = t * 8 + e;               // 0..2047
            int tq   = idx >> 9;                // 0..3
            int lane = (idx >> 3) & 63;
            int j    = idx & 7;
            int row = lane & 15, grp = lane >> 4;
            int n = tq * 16 + row;
            int k = grp * 8 + j;
            wpb[idx] = (k < CIN_) ? f2bf(w_pn[k * C_ + n]) : 0;
        }
        return;
    }

    __shared__ int lds[256];
    __shared__ int sbase;
    int tid  = threadIdx.x;
    int base = blockIdx.x * 1024 + tid * 4;
    i32x4 c = *(const i32x4*)(cnt + base);
    int s1 = c[0] + c[1], s2 = s1 + c[2], s3 = s2 + c[3];
    lds[tid] = s3;
    __syncthreads();
    #pragma unroll
    for (int d = 1; d < 256; d <<= 1) {
        int v = (tid >= d) ? lds[tid - d] : 0;
        __syncthreads();
        if (tid >= d) lds[tid] += v;
        __syncthreads();
    }
    if (tid == 0) sbase = atomicAdd(gcursor, lds[255]);
    __syncthreads();
    int o = sbase + (tid == 0 ? 0 : lds[tid - 1]);
    i32x4 e;
    e[0] = o; e[1] = o + c[0]; e[2] = o + s1; e[3] = o + s2;
    *(i32x4*)(off + base) = e;
    *(i32x4*)(cur + base) = e;
}

// ---------------- Stage 3: z = feat @ w_pn via MFMA, scattered to voxel-sorted zs ----
__global__ __launch_bounds__(256) void k_z(
    const float* __restrict__ feat,
    const int* __restrict__ indices,
    const int* __restrict__ paddings,
    const unsigned short* __restrict__ wpb,   // [4][64][8]
    int* __restrict__ cur,
    unsigned short* __restrict__ zs)          // bf16 [NPT_][C_] voxel-sorted
{
    int lane = threadIdx.x & 63;
    int wid  = (blockIdx.x * 256 + threadIdx.x) >> 6;
    int p0   = wid * 16;                      // NPT_ % 16 == 0
    int row  = lane & 15;
    int grp  = lane >> 4;

    int slot = -1;
    if (lane < 16) {
        int pt = p0 + lane;
        if (paddings[pt] == 0) {
            int v = (pt / P_) * S_ + indices[pt];
            slot = atomicAdd(&cur[v], 1);
        }
    }

    const float* f = feat + (size_t)(p0 + row) * CIN_;
    short8 a;
    #pragma unroll
    for (int j = 0; j < 8; ++j) {
        int k = grp * 8 + j;
        a[j] = (short)(k < CIN_ ? f2bf(f[k]) : 0);
    }

    short8 bfrag[4];
    #pragma unroll
    for (int t = 0; t < 4; ++t)
        bfrag[t] = *(const short8*)(wpb + ((size_t)t * 64 + lane) * 8);

    f32x4 acc[4];
    #pragma unroll
    for (int t = 0; t < 4; ++t) acc[t] = (f32x4){0.f, 0.f, 0.f, 0.f};
    #pragma unroll
    for (int t = 0; t < 4; ++t)
        acc[t] = __builtin_amdgcn_mfma_f32_16x16x32_bf16(a, bfrag[t], acc[t], 0, 0, 0);

    #pragma unroll
    for (int r = 0; r < 4; ++r) {
        int sm = __shfl(slot, grp * 4 + r);
        if (sm >= 0) {
            unsigned short* op = zs + (size_t)sm * C_;
            #pragma unroll
            for (int t = 0; t < 4; ++t)
                op[t * 16 + row] = f2bf(acc[t][r]);
        }
    }
}

// ---------------- Stage 4: FUSED reduce-max + BN1 + ReLU + 1x1conv + BN2 + ReLU ----
// one wave = 16 voxels; stores ONLY occupied rows (empty rows never read downstream)
__global__ __launch_bounds__(256) void k_redconv(
    const unsigned short* __restrict__ zs,
    const int* __restrict__ cnt,
    const int* __restrict__ off,
    const float* __restrict__ s1v, const float* __restrict__ o1v,
    const unsigned short* __restrict__ cwb,   // [8][64][8]
    const float* __restrict__ scv, const float* __restrict__ shv,
    unsigned short* __restrict__ grid)        // bf16 [NVOX_][C_], occupied rows only
{
    int lane = threadIdx.x & 63;
    int wid  = (blockIdx.x * 256 + threadIdx.x) >> 6;
    int v0   = wid * 16;                      // NVOX_/16 waves exactly
    int m    = lane & 15;
    int grp  = lane >> 4;

    int vi = v0 + m;
    int ci = cnt[vi];
    if (__all(ci == 0)) return;               // all 16 voxels empty (~0.4%)
    int oi = off[vi];

    float mx[16];
    #pragma unroll
    for (int i = 0; i < 16; ++i) mx[i] = -1e30f;

    for (int j = 0; ; ++j) {
        bool live = j < ci;
        if (!__any(live)) break;
        const unsigned short* zr =
            zs + (size_t)(oi + (live ? j : 0)) * C_ + grp * 8;
        short8 lo = *(const short8*)(zr);         // channels grp*8..+7
        short8 hi = *(const short8*)(zr + 32);    // channels 32+grp*8..+7
        if (live) {
            #pragma unroll
            for (int jj = 0; jj < 8; ++jj) {
                mx[jj]     = fmaxf(mx[jj],     bf2f((unsigned short)lo[jj]));
                mx[8 + jj] = fmaxf(mx[8 + jj], bf2f((unsigned short)hi[jj]));
            }
        }
    }

    // BN1 + ReLU -> A fragments (empty voxel: -1e30 -> relu -> 0 exactly)
    short8 a[2];
    #pragma unroll
    for (int jj = 0; jj < 8; ++jj) {
        int c0 = grp * 8 + jj;
        int c1 = 32 + grp * 8 + jj;
        a[0][jj] = (short)f2bf(fmaxf(mx[jj]     * s1v[c0] + o1v[c0], 0.f));
        a[1][jj] = (short)f2bf(fmaxf(mx[8 + jj] * s1v[c1] + o1v[c1], 0.f));
    }

    short8 bfrag[4][2];
    #pragma unroll
    for (int t = 0; t < 4; ++t)
        #pragma unroll
        for (int ks = 0; ks < 2; ++ks)
            bfrag[t][ks] = *(const short8*)(cwb + ((size_t)(t * 2 + ks) * 64 + lane) * 8);

    f32x4 acc[4];
    #pragma unroll
    for (int t = 0; t < 4; ++t) acc[t] = (f32x4){0.f, 0.f, 0.f, 0.f};
    #pragma unroll
    for (int t = 0; t < 4; ++t) {
        acc[t] = __builtin_amdgcn_mfma_f32_16x16x32_bf16(a[0], bfrag[t][0], acc[t], 0, 0, 0);
        acc[t] = __builtin_amdgcn_mfma_f32_16x16x32_bf16(a[1], bfrag[t][1], acc[t], 0, 0, 0);
    }

    // BN2 + ReLU epilogue: C[mr = grp*4+r][n = t*16+m] -> grid[v0+mr] iff occupied
    float sc[4], sh[4];
    #pragma unroll
    for (int t = 0; t < 4; ++t) {
        int n = t * 16 + m;
        sc[t] = scv[n];
        sh[t] = shv[n];
    }
    #pragma unroll
    for (int r = 0; r < 4; ++r) {
        int cv = __shfl(ci, grp * 4 + r);     // cnt of row v0+grp*4+r
        if (cv > 0) {
            unsigned short* op = grid + (size_t)(v0 + grp * 4 + r) * C_;
            #pragma unroll
            for (int t = 0; t < 4; ++t) {
                float val = fmaxf(acc[t][r] * sc[t] + sh[t], 0.f);
                op[t * 16 + m] = f2bf(val);
            }
        }
    }
}

// ---------------- Stage 5: bilinear gather, 8 points/wave, cnt-gated reads ----------
__global__ __launch_bounds__(256) void k_gather8(
    const unsigned short* __restrict__ grid,   // bf16, occupied rows only
    const int* __restrict__ cnt,
    const float* __restrict__ vxyz,
    const float* __restrict__ shv,
    float* __restrict__ out)                   // f32 output
{
    int lane = threadIdx.x & 63;
    int gw   = (blockIdx.x * 256 + threadIdx.x) >> 6;
    int p0   = gw * 8;                          // NPT_ % 8 == 0
    if (p0 >= NPT_) return;

    float cst = fmaxf(shv[lane], 0.f);          // conv(0)+BN2+ReLU (f32, == ref path)

    #pragma unroll
    for (int k = 0; k < 8; ++k) {
        int pt = p0 + k;
        int b  = pt / P_;
        float xq = vxyz[(size_t)pt * 3 + 0];
        float yq = vxyz[(size_t)pt * 3 + 1];
        int x0 = (int)floorf(xq); x0 = min(max(x0, 0), W_ - 1);
        int x1 = min(x0 + 1, W_ - 1);
        int y0 = (int)floorf(yq); y0 = min(max(y0, 0), H_ - 1);
        int y1 = min(y0 + 1, H_ - 1);
        float x0f = (float)x0, x1f = (float)x1, y0f = (float)y0, y1f = (float)y1;
        float wa = (x1f - xq) * (y1f - yq);
        float wb = (x1f - xq) * (yq - y0f);
        float wc = (xq - x0f) * (y1f - yq);
        float wd = (xq - x0f) * (yq - y0f);

        int ia = y0 * W_ + x0, ib = y1 * W_ + x0, ic = y0 * W_ + x1, id = y1 * W_ + x1;
        const int* cb = cnt + (size_t)b * S_;
        const unsigned short* g = grid + (size_t)b * S_ * C_;
        // corner ids are wave-uniform -> cnt loads broadcast, branches uniform
        int ca = cb[ia], cbv = cb[ib], cc = cb[ic], cd = cb[id];
        float Ia = ca  > 0 ? bf2f(g[(size_t)ia * C_ + lane]) : cst;
        float Ib = cbv > 0 ? bf2f(g[(size_t)ib * C_ + lane]) : cst;
        float Ic = cc  > 0 ? bf2f(g[(size_t)ic * C_ + lane]) : cst;
        float Id = cd  > 0 ? bf2f(g[(size_t)id * C_ + lane]) : cst;

        out[(size_t)pt * C_ + lane] = wa * Ia + wb * Ib + wc * Ic + wd * Id;
    }
}

extern "C" void kernel_launch(void* const* d_in, const int* in_sizes, int n_in,
                              void* d_out, int out_size, void* d_ws, size_t ws_size,
                              hipStream_t stream)
{
    const float* feat     = (const float*)d_in[1];
    const int*   indices  = (const int*)d_in[3];
    const int*   paddings = (const int*)d_in[4];
    const float* vxyz     = (const float*)d_in[5];
    const float* w_pn     = (const float*)d_in[6];
    const float* g1       = (const float*)d_in[7];
    const float* b1       = (const float*)d_in[8];
    const float* m1       = (const float*)d_in[9];
    const float* v1       = (const float*)d_in[10];
    const float* cw       = (const float*)d_in[11];
    const float* g2       = (const float*)d_in[12];
    const float* b2       = (const float*)d_in[13];
    const float* m2       = (const float*)d_in[14];
    const float* v2       = (const float*)d_in[15];

    // ws layout: grid 67.1MB | zs 25.6MB | cnt 2MB | off 2MB | cur 2MB |
    //            gcursor 16B | cwb 8KB | wpb 4KB | s1v/o1v/scv/shv 4x256B
    char* p = (char*)d_ws;
    unsigned short* grid = (unsigned short*)p;  p += (size_t)NVOX_ * C_ * 2;
    unsigned short* zs   = (unsigned short*)p;  p += (size_t)NPT_ * C_ * 2;
    int* cnt  = (int*)p;  p += (size_t)NVOX_ * 4;
    int* off  = (int*)p;  p += (size_t)NVOX_ * 4;
    int* cur  = (int*)p;  p += (size_t)NVOX_ * 4;
    int* gcur = (int*)p;  p += 16;
    unsigned short* cwb = (unsigned short*)p;  p += 8 * 64 * 8 * 2;
    unsigned short* wpb = (unsigned short*)p;  p += 4 * 64 * 8 * 2;
    float* s1v = (float*)p;  p += 64 * 4;
    float* o1v = (float*)p;  p += 64 * 4;
    float* scv = (float*)p;  p += 64 * 4;
    float* shv = (float*)p;

    hipMemsetAsync(cnt, 0, (size_t)NVOX_ * 4, stream);
    hipMemsetAsync(gcur, 0, 4, stream);

    k_hist<<<(NPT_ + 255) / 256, 256, 0, stream>>>(indices, paddings, cnt);

    k_offsets<<<513, 256, 0, stream>>>(cnt, off, cur, gcur,
        cw, w_pn, g1, b1, m1, v1, g2, b2, m2, v2,
        cwb, wpb, s1v, o1v, scv, shv);

    k_z<<<3125, 256, 0, stream>>>(feat, indices, paddings, wpb, cur, zs);

    k_redconv<<<8192, 256, 0, stream>>>(zs, cnt, off, s1v, o1v, cwb, scv, shv, grid);

    k_gather8<<<6250, 256, 0, stream>>>(grid, cnt, vxyz, shv, (float*)d_out);
}

// Round 13
// 105.239 us; speedup vs baseline: 1.1227x; 1.1227x over previous
//
#include <hip/hip_runtime.h>
#include <hip/hip_bf16.h>

#define B_ 2
#define P_ 100000
#define CIN_ 23
#define C_ 64
#define H_ 512
#define W_ 512
#define S_ (H_*W_)       // 262144
#define NPT_ (B_*P_)     // 200000
#define NVOX_ (B_*S_)    // 524288

typedef __attribute__((ext_vector_type(8))) short short8;
typedef __attribute__((ext_vector_type(4))) float f32x4;
typedef __attribute__((ext_vector_type(4))) int i32x4;

__device__ inline unsigned short f2bf(float f) {
    union { __hip_bfloat16 h; unsigned short u; } cv;
    cv.h = __float2bfloat16(f);
    return cv.u;
}
__device__ inline float bf2f(unsigned short u) {
    union { unsigned int i; float f; } cv;
    cv.i = ((unsigned int)u) << 16;
    return cv.f;
}

// ---------------- Stage 1: histogram ----------------
__global__ __launch_bounds__(256) void k_hist(
    const int* __restrict__ indices,
    const int* __restrict__ paddings,
    int* __restrict__ cnt)
{
    int pt = blockIdx.x * 256 + threadIdx.x;
    if (pt >= NPT_) return;
    if (paddings[pt] != 0) return;
    int v = (pt / P_) * S_ + indices[pt];
    atomicAdd(&cnt[v], 1);
}

// ---------------- Stage 2: exclusive-scan offsets + (block 512) param prep ----------
__global__ __launch_bounds__(256) void k_offsets(
    const int* __restrict__ cnt,
    int* __restrict__ off,
    int* __restrict__ cur,
    int* __restrict__ gcursor,
    const float* __restrict__ conv_w,
    const float* __restrict__ w_pn,
    const float* __restrict__ g1, const float* __restrict__ b1,
    const float* __restrict__ m1, const float* __restrict__ v1,
    const float* __restrict__ g2, const float* __restrict__ b2,
    const float* __restrict__ m2, const float* __restrict__ v2,
    unsigned short* __restrict__ cwb,   // [8][64][8] bf16 conv-W fragments
    unsigned short* __restrict__ wpb,   // [4][64][8] bf16 (w_pn * s1) fragments
    float* __restrict__ s1v, float* __restrict__ o1v,
    float* __restrict__ scv, float* __restrict__ shv)
{
    if (blockIdx.x >= 512) {            // ---- prep block ----
        int t = threadIdx.x;
        if (t < 64) {
            float s = g1[t] * rsqrtf(v1[t] + 1e-5f);
            s1v[t] = s;
            o1v[t] = b1[t] - m1[t] * s;
            float s2 = g2[t] * rsqrtf(v2[t] + 1e-3f);
            scv[t] = s2;
            shv[t] = b2[t] - m2[t] * s2;
        }
        #pragma unroll
        for (int e = 0; e < 16; ++e) {
            int idx  = t * 16 + e;              // 0..4095
            int f    = idx >> 9;                // 0..7
            int lane = (idx >> 3) & 63;
            int j    = idx & 7;
            int tq = f >> 1, ks = f & 1;
            int row = lane & 15, grp = lane >> 4;
            cwb[idx] = f2bf(conv_w[(tq * 16 + row) * 64 + ks * 32 + grp * 8 + j]);
        }
        #pragma unroll
        for (int e = 0; e < 8; ++e) {
            int idx  = t * 8 + e;               // 0..2047
            int tq   = idx >> 9;                // 0..3
            int lane = (idx >> 3) & 63;
            int j    = idx & 7;
            int row = lane & 15, grp = lane >> 4;
            int n = tq * 16 + row;
            int k = grp * 8 + j;
            // fold BN1 scale (s1[n] > 0): max(z*s1) == max(z)*s1
            float s1n = g1[n] * rsqrtf(v1[n] + 1e-5f);
            wpb[idx] = (k < CIN_) ? f2bf(w_pn[k * C_ + n] * s1n) : 0;
        }
        return;
    }

    __shared__ int lds[256];
    __shared__ int sbase;
    int tid  = threadIdx.x;
    int base = blockIdx.x * 1024 + tid * 4;
    i32x4 c = *(const i32x4*)(cnt + base);
    int s1 = c[0] + c[1], s2 = s1 + c[2], s3 = s2 + c[3];
    lds[tid] = s3;
    __syncthreads();
    #pragma unroll
    for (int d = 1; d < 256; d <<= 1) {
        int v = (tid >= d) ? lds[tid - d] : 0;
        __syncthreads();
        if (tid >= d) lds[tid] += v;
        __syncthreads();
    }
    if (tid == 0) sbase = atomicAdd(gcursor, lds[255]);
    __syncthreads();
    int o = sbase + (tid == 0 ? 0 : lds[tid - 1]);
    i32x4 e;
    e[0] = o; e[1] = o + c[0]; e[2] = o + s1; e[3] = o + s2;
    *(i32x4*)(off + base) = e;
    *(i32x4*)(cur + base) = e;
}

// ---------------- Stage 3: z = feat @ (w_pn*s1) via MFMA -> voxel-sorted zs ----------
__global__ __launch_bounds__(256) void k_z(
    const float* __restrict__ feat,
    const int* __restrict__ indices,
    const int* __restrict__ paddings,
    const unsigned short* __restrict__ wpb,   // [4][64][8]
    int* __restrict__ cur,
    unsigned short* __restrict__ zs)          // bf16 [NPT_][C_] voxel-sorted
{
    int lane = threadIdx.x & 63;
    int wid  = (blockIdx.x * 256 + threadIdx.x) >> 6;
    int p0   = wid * 16;                      // NPT_ % 16 == 0
    int row  = lane & 15;
    int grp  = lane >> 4;

    int slot = -1;
    if (lane < 16) {
        int pt = p0 + lane;
        if (paddings[pt] == 0) {
            int v = (pt / P_) * S_ + indices[pt];
            slot = atomicAdd(&cur[v], 1);
        }
    }

    const float* f = feat + (size_t)(p0 + row) * CIN_;
    short8 a;
    #pragma unroll
    for (int j = 0; j < 8; ++j) {
        int k = grp * 8 + j;
        a[j] = (short)(k < CIN_ ? f2bf(f[k]) : 0);
    }

    short8 bfrag[4];
    #pragma unroll
    for (int t = 0; t < 4; ++t)
        bfrag[t] = *(const short8*)(wpb + ((size_t)t * 64 + lane) * 8);

    f32x4 acc[4];
    #pragma unroll
    for (int t = 0; t < 4; ++t) acc[t] = (f32x4){0.f, 0.f, 0.f, 0.f};
    #pragma unroll
    for (int t = 0; t < 4; ++t)
        acc[t] = __builtin_amdgcn_mfma_f32_16x16x32_bf16(a, bfrag[t], acc[t], 0, 0, 0);

    #pragma unroll
    for (int r = 0; r < 4; ++r) {
        int sm = __shfl(slot, grp * 4 + r);
        if (sm >= 0) {
            unsigned short* op = zs + (size_t)sm * C_;
            #pragma unroll
            for (int t = 0; t < 4; ++t)
                op[t * 16 + row] = f2bf(acc[t][r]);
        }
    }
}

// ---------------- Stage 4: FUSED reduce-max + BN1-off + ReLU + 1x1conv + BN2 + ReLU --
// one wave = 16 voxels; stores ONLY occupied rows
__global__ __launch_bounds__(256) void k_redconv(
    const unsigned short* __restrict__ zs,
    const int* __restrict__ cnt,
    const int* __restrict__ off,
    const float* __restrict__ o1v,
    const unsigned short* __restrict__ cwb,   // [8][64][8]
    const float* __restrict__ scv, const float* __restrict__ shv,
    unsigned short* __restrict__ grid)        // bf16 [NVOX_][C_], occupied rows only
{
    int lane = threadIdx.x & 63;
    int wid  = (blockIdx.x * 256 + threadIdx.x) >> 6;
    int v0   = wid * 16;                      // NVOX_/16 waves exactly
    int m    = lane & 15;
    int grp  = lane >> 4;

    int vi = v0 + m;
    int ci = cnt[vi];
    if (__all(ci == 0)) return;               // all 16 voxels empty (~0.4%)
    int oi = off[vi];

    float mx[16];
    #pragma unroll
    for (int i = 0; i < 16; ++i) mx[i] = -1e30f;

    for (int j = 0; ; ++j) {
        bool live = j < ci;
        if (!__any(live)) break;
        const unsigned short* zr =
            zs + (size_t)(oi + (live ? j : 0)) * C_ + grp * 8;
        short8 lo = *(const short8*)(zr);         // channels grp*8..+7 (pre-scaled by s1)
        short8 hi = *(const short8*)(zr + 32);    // channels 32+grp*8..+7
        if (live) {
            #pragma unroll
            for (int jj = 0; jj < 8; ++jj) {
                mx[jj]     = fmaxf(mx[jj],     bf2f((unsigned short)lo[jj]));
                mx[8 + jj] = fmaxf(mx[8 + jj], bf2f((unsigned short)hi[jj]));
            }
        }
    }

    // + BN1 offset + ReLU -> A fragments (empty voxel: -1e30 -> relu -> 0 exactly)
    short8 a[2];
    #pragma unroll
    for (int jj = 0; jj < 8; ++jj) {
        int c0 = grp * 8 + jj;
        int c1 = 32 + grp * 8 + jj;
        a[0][jj] = (short)f2bf(fmaxf(mx[jj]     + o1v[c0], 0.f));
        a[1][jj] = (short)f2bf(fmaxf(mx[8 + jj] + o1v[c1], 0.f));
    }

    short8 bfrag[4][2];
    #pragma unroll
    for (int t = 0; t < 4; ++t)
        #pragma unroll
        for (int ks = 0; ks < 2; ++ks)
            bfrag[t][ks] = *(const short8*)(cwb + ((size_t)(t * 2 + ks) * 64 + lane) * 8);

    f32x4 acc[4];
    #pragma unroll
    for (int t = 0; t < 4; ++t) acc[t] = (f32x4){0.f, 0.f, 0.f, 0.f};
    #pragma unroll
    for (int t = 0; t < 4; ++t) {
        acc[t] = __builtin_amdgcn_mfma_f32_16x16x32_bf16(a[0], bfrag[t][0], acc[t], 0, 0, 0);
        acc[t] = __builtin_amdgcn_mfma_f32_16x16x32_bf16(a[1], bfrag[t][1], acc[t], 0, 0, 0);
    }

    float sc[4], sh[4];
    #pragma unroll
    for (int t = 0; t < 4; ++t) {
        int n = t * 16 + m;
        sc[t] = scv[n];
        sh[t] = shv[n];
    }
    #pragma unroll
    for (int r = 0; r < 4; ++r) {
        int cv = __shfl(ci, grp * 4 + r);     // cnt of row v0+grp*4+r
        if (cv > 0) {
            unsigned short* op = grid + (size_t)(v0 + grp * 4 + r) * C_;
            #pragma unroll
            for (int t = 0; t < 4; ++t) {
                float val = fmaxf(acc[t][r] * sc[t] + sh[t], 0.f);
                op[t * 16 + m] = f2bf(val);
            }
        }
    }
}

// ---------------- Stage 5: bilinear gather, 8 pts/wave, BRANCHLESS cnt-select ----------
// all row + cnt loads unconditional & independent (full MLP); select after return.
// Empty rows hold workspace poison (finite tiny bf16) -> discarded by select.
__global__ __launch_bounds__(256) void k_gather8(
    const unsigned short* __restrict__ grid,   // bf16, occupied rows only
    const int* __restrict__ cnt,
    const float* __restrict__ vxyz,
    const float* __restrict__ shv,
    float* __restrict__ out)                   // f32 output
{
    int lane = threadIdx.x & 63;
    int gw   = (blockIdx.x * 256 + threadIdx.x) >> 6;
    int p0   = gw * 8;                          // NPT_ % 8 == 0
    if (p0 >= NPT_) return;

    float cst = fmaxf(shv[lane], 0.f);          // conv(0)+BN2+ReLU (f32, == ref path)

    #pragma unroll
    for (int k = 0; k < 8; ++k) {
        int pt = p0 + k;
        int b  = pt / P_;
        float xq = vxyz[(size_t)pt * 3 + 0];
        float yq = vxyz[(size_t)pt * 3 + 1];
        int x0 = (int)floorf(xq); x0 = min(max(x0, 0), W_ - 1);
        int x1 = min(x0 + 1, W_ - 1);
        int y0 = (int)floorf(yq); y0 = min(max(y0, 0), H_ - 1);
        int y1 = min(y0 + 1, H_ - 1);
        float x0f = (float)x0, x1f = (float)x1, y0f = (float)y0, y1f = (float)y1;
        float wa = (x1f - xq) * (y1f - yq);
        float wb = (x1f - xq) * (yq - y0f);
        float wc = (xq - x0f) * (y1f - yq);
        float wd = (xq - x0f) * (yq - y0f);

        int ia = y0 * W_ + x0, ib = y1 * W_ + x0, ic = y0 * W_ + x1, id = y1 * W_ + x1;
        const int* cb = cnt + (size_t)b * S_;
        const unsigned short* g = grid + (size_t)b * S_ * C_;
        // unconditional loads: rows and cnts all independent, issue together
        float Ra = bf2f(g[(size_t)ia * C_ + lane]);
        float Rb = bf2f(g[(size_t)ib * C_ + lane]);
        float Rc = bf2f(g[(size_t)ic * C_ + lane]);
        float Rd = bf2f(g[(size_t)id * C_ + lane]);
        int ca = cb[ia], cbv = cb[ib], cc = cb[ic], cd = cb[id];
        float Ia = ca  > 0 ? Ra : cst;          // cndmask, no branch
        float Ib = cbv > 0 ? Rb : cst;
        float Ic = cc  > 0 ? Rc : cst;
        float Id = cd  > 0 ? Rd : cst;

        out[(size_t)pt * C_ + lane] = wa * Ia + wb * Ib + wc * Ic + wd * Id;
    }
}

extern "C" void kernel_launch(void* const* d_in, const int* in_sizes, int n_in,
                              void* d_out, int out_size, void* d_ws, size_t ws_size,
                              hipStream_t stream)
{
    const float* feat     = (const float*)d_in[1];
    const int*   indices  = (const int*)d_in[3];
    const int*   paddings = (const int*)d_in[4];
    const float* vxyz     = (const float*)d_in[5];
    const float* w_pn     = (const float*)d_in[6];
    const float* g1       = (const float*)d_in[7];
    const float* b1       = (const float*)d_in[8];
    const float* m1       = (const float*)d_in[9];
    const float* v1       = (const float*)d_in[10];
    const float* cw       = (const float*)d_in[11];
    const float* g2       = (const float*)d_in[12];
    const float* b2       = (const float*)d_in[13];
    const float* m2       = (const float*)d_in[14];
    const float* v2       = (const float*)d_in[15];

    // ws layout: grid 67.1MB | zs 25.6MB | cnt 2MB | off 2MB | cur 2MB |
    //            gcursor 16B | cwb 8KB | wpb 4KB | s1v/o1v/scv/shv 4x256B
    char* p = (char*)d_ws;
    unsigned short* grid = (unsigned short*)p;  p += (size_t)NVOX_ * C_ * 2;
    unsigned short* zs   = (unsigned short*)p;  p += (size_t)NPT_ * C_ * 2;
    int* cnt  = (int*)p;  p += (size_t)NVOX_ * 4;
    int* off  = (int*)p;  p += (size_t)NVOX_ * 4;
    int* cur  = (int*)p;  p += (size_t)NVOX_ * 4;
    int* gcur = (int*)p;  p += 16;
    unsigned short* cwb = (unsigned short*)p;  p += 8 * 64 * 8 * 2;
    unsigned short* wpb = (unsigned short*)p;  p += 4 * 64 * 8 * 2;
    float* s1v = (float*)p;  p += 64 * 4;
    float* o1v = (float*)p;  p += 64 * 4;
    float* scv = (float*)p;  p += 64 * 4;
    float* shv = (float*)p;

    hipMemsetAsync(cnt, 0, (size_t)NVOX_ * 4, stream);
    hipMemsetAsync(gcur, 0, 4, stream);

    k_hist<<<(NPT_ + 255) / 256, 256, 0, stream>>>(indices, paddings, cnt);

    k_offsets<<<513, 256, 0, stream>>>(cnt, off, cur, gcur,
        cw, w_pn, g1, b1, m1, v1, g2, b2, m2, v2,
        cwb, wpb, s1v, o1v, scv, shv);

    k_z<<<3125, 256, 0, stream>>>(feat, indices, paddings, wpb, cur, zs);

    k_redconv<<<8192, 256, 0, stream>>>(zs, cnt, off, o1v, cwb, scv, shv, grid);

    k_gather8<<<6250, 256, 0, stream>>>(grid, cnt, vxyz, shv, (float*)d_out);
}

// Round 14
// 102.171 us; speedup vs baseline: 1.1564x; 1.0300x over previous
//
#include <hip/hip_runtime.h>
#include <hip/hip_bf16.h>

#define B_ 2
#define P_ 100000
#define CIN_ 23
#define C_ 64
#define H_ 512
#define W_ 512
#define S_ (H_*W_)       // 262144
#define NPT_ (B_*P_)     // 200000
#define NVOX_ (B_*S_)    // 524288

typedef __attribute__((ext_vector_type(8))) short short8;
typedef __attribute__((ext_vector_type(4))) float f32x4;
typedef __attribute__((ext_vector_type(4))) int i32x4;

__device__ inline unsigned short f2bf(float f) {
    union { __hip_bfloat16 h; unsigned short u; } cv;
    cv.h = __float2bfloat16(f);
    return cv.u;
}
__device__ inline float bf2f(unsigned short u) {
    union { unsigned int i; float f; } cv;
    cv.i = ((unsigned int)u) << 16;
    return cv.f;
}
// expand packed 2xbf16 word -> two floats (1 VALU op each)
__device__ inline void bf2x(unsigned int u, float& lo, float& hi) {
    union { unsigned int i; float f; } a, b;
    a.i = u << 16;
    b.i = u & 0xffff0000u;
    lo = a.f; hi = b.f;
}

// ---------------- Stage 1: histogram ----------------
__global__ __launch_bounds__(256) void k_hist(
    const int* __restrict__ indices,
    const int* __restrict__ paddings,
    int* __restrict__ cnt)
{
    int pt = blockIdx.x * 256 + threadIdx.x;
    if (pt >= NPT_) return;
    if (paddings[pt] != 0) return;
    int v = (pt / P_) * S_ + indices[pt];
    atomicAdd(&cnt[v], 1);
}

// ---------------- Stage 2: exclusive-scan offsets + (block 512) param prep ----------
__global__ __launch_bounds__(256) void k_offsets(
    const int* __restrict__ cnt,
    int* __restrict__ off,
    int* __restrict__ cur,
    int* __restrict__ gcursor,
    const float* __restrict__ conv_w,
    const float* __restrict__ w_pn,
    const float* __restrict__ g1, const float* __restrict__ b1,
    const float* __restrict__ m1, const float* __restrict__ v1,
    const float* __restrict__ g2, const float* __restrict__ b2,
    const float* __restrict__ m2, const float* __restrict__ v2,
    unsigned short* __restrict__ cwb,   // [8][64][8] bf16 conv-W fragments
    unsigned short* __restrict__ wpb,   // [4][64][8] bf16 (w_pn * s1) fragments
    float* __restrict__ o1v,
    float* __restrict__ scv, float* __restrict__ shv)
{
    if (blockIdx.x >= 512) {            // ---- prep block ----
        int t = threadIdx.x;
        if (t < 64) {
            float s = g1[t] * rsqrtf(v1[t] + 1e-5f);
            o1v[t] = b1[t] - m1[t] * s;
            float s2 = g2[t] * rsqrtf(v2[t] + 1e-3f);
            scv[t] = s2;
            shv[t] = b2[t] - m2[t] * s2;
        }
        #pragma unroll
        for (int e = 0; e < 16; ++e) {
            int idx  = t * 16 + e;              // 0..4095
            int f    = idx >> 9;                // 0..7
            int lane = (idx >> 3) & 63;
            int j    = idx & 7;
            int tq = f >> 1, ks = f & 1;
            int row = lane & 15, grp = lane >> 4;
            cwb[idx] = f2bf(conv_w[(tq * 16 + row) * 64 + ks * 32 + grp * 8 + j]);
        }
        #pragma unroll
        for (int e = 0; e < 8; ++e) {
            int idx  = t * 8 + e;               // 0..2047
            int tq   = idx >> 9;                // 0..3
            int lane = (idx >> 3) & 63;
            int j    = idx & 7;
            int row = lane & 15, grp = lane >> 4;
            int n = tq * 16 + row;
            int k = grp * 8 + j;
            // fold BN1 scale (s1[n] > 0): max(z*s1) == max(z)*s1
            float s1n = g1[n] * rsqrtf(v1[n] + 1e-5f);
            wpb[idx] = (k < CIN_) ? f2bf(w_pn[k * C_ + n] * s1n) : 0;
        }
        return;
    }

    __shared__ int lds[256];
    __shared__ int sbase;
    int tid  = threadIdx.x;
    int base = blockIdx.x * 1024 + tid * 4;
    i32x4 c = *(const i32x4*)(cnt + base);
    int s1 = c[0] + c[1], s2 = s1 + c[2], s3 = s2 + c[3];
    lds[tid] = s3;
    __syncthreads();
    #pragma unroll
    for (int d = 1; d < 256; d <<= 1) {
        int v = (tid >= d) ? lds[tid - d] : 0;
        __syncthreads();
        if (tid >= d) lds[tid] += v;
        __syncthreads();
    }
    if (tid == 0) sbase = atomicAdd(gcursor, lds[255]);
    __syncthreads();
    int o = sbase + (tid == 0 ? 0 : lds[tid - 1]);
    i32x4 e;
    e[0] = o; e[1] = o + c[0]; e[2] = o + s1; e[3] = o + s2;
    *(i32x4*)(off + base) = e;
    *(i32x4*)(cur + base) = e;
}

// ---------------- Stage 3: z = feat @ (w_pn*s1) via MFMA -> voxel-sorted zs ----------
__global__ __launch_bounds__(256) void k_z(
    const float* __restrict__ feat,
    const int* __restrict__ indices,
    const int* __restrict__ paddings,
    const unsigned short* __restrict__ wpb,   // [4][64][8]
    int* __restrict__ cur,
    unsigned short* __restrict__ zs)          // bf16 [NPT_][C_] voxel-sorted
{
    int lane = threadIdx.x & 63;
    int wid  = (blockIdx.x * 256 + threadIdx.x) >> 6;
    int p0   = wid * 16;                      // NPT_ % 16 == 0
    int row  = lane & 15;
    int grp  = lane >> 4;

    int slot = -1;
    if (lane < 16) {
        int pt = p0 + lane;
        if (paddings[pt] == 0) {
            int v = (pt / P_) * S_ + indices[pt];
            slot = atomicAdd(&cur[v], 1);
        }
    }

    const float* f = feat + (size_t)(p0 + row) * CIN_;
    short8 a;
    #pragma unroll
    for (int j = 0; j < 8; ++j) {
        int k = grp * 8 + j;
        a[j] = (short)(k < CIN_ ? f2bf(f[k]) : 0);
    }

    short8 bfrag[4];
    #pragma unroll
    for (int t = 0; t < 4; ++t)
        bfrag[t] = *(const short8*)(wpb + ((size_t)t * 64 + lane) * 8);

    f32x4 acc[4];
    #pragma unroll
    for (int t = 0; t < 4; ++t) acc[t] = (f32x4){0.f, 0.f, 0.f, 0.f};
    #pragma unroll
    for (int t = 0; t < 4; ++t)
        acc[t] = __builtin_amdgcn_mfma_f32_16x16x32_bf16(a, bfrag[t], acc[t], 0, 0, 0);

    #pragma unroll
    for (int r = 0; r < 4; ++r) {
        int sm = __shfl(slot, grp * 4 + r);
        if (sm >= 0) {
            unsigned short* op = zs + (size_t)sm * C_;
            #pragma unroll
            for (int t = 0; t < 4; ++t)
                op[t * 16 + row] = f2bf(acc[t][r]);
        }
    }
}

// ---------------- Stage 4: FUSED reduce-max + BN1-off + ReLU + 1x1conv + BN2 + ReLU --
// one wave = 16 voxels; stores ONLY occupied rows
__global__ __launch_bounds__(256) void k_redconv(
    const unsigned short* __restrict__ zs,
    const int* __restrict__ cnt,
    const int* __restrict__ off,
    const float* __restrict__ o1v,
    const unsigned short* __restrict__ cwb,   // [8][64][8]
    const float* __restrict__ scv, const float* __restrict__ shv,
    unsigned short* __restrict__ grid)        // bf16 [NVOX_][C_], occupied rows only
{
    int lane = threadIdx.x & 63;
    int wid  = (blockIdx.x * 256 + threadIdx.x) >> 6;
    int v0   = wid * 16;                      // NVOX_/16 waves exactly
    int m    = lane & 15;
    int grp  = lane >> 4;

    int vi = v0 + m;
    int ci = cnt[vi];
    if (__all(ci == 0)) return;               // all 16 voxels empty (~0.4%)
    int oi = off[vi];

    float mx[16];
    #pragma unroll
    for (int i = 0; i < 16; ++i) mx[i] = -1e30f;

    for (int j = 0; ; ++j) {
        bool live = j < ci;
        if (!__any(live)) break;
        const unsigned short* zr =
            zs + (size_t)(oi + (live ? j : 0)) * C_ + grp * 8;
        short8 lo = *(const short8*)(zr);         // channels grp*8..+7 (pre-scaled by s1)
        short8 hi = *(const short8*)(zr + 32);    // channels 32+grp*8..+7
        if (live) {
            #pragma unroll
            for (int jj = 0; jj < 8; ++jj) {
                mx[jj]     = fmaxf(mx[jj],     bf2f((unsigned short)lo[jj]));
                mx[8 + jj] = fmaxf(mx[8 + jj], bf2f((unsigned short)hi[jj]));
            }
        }
    }

    // + BN1 offset + ReLU -> A fragments (empty voxel: -1e30 -> relu -> 0 exactly)
    short8 a[2];
    #pragma unroll
    for (int jj = 0; jj < 8; ++jj) {
        int c0 = grp * 8 + jj;
        int c1 = 32 + grp * 8 + jj;
        a[0][jj] = (short)f2bf(fmaxf(mx[jj]     + o1v[c0], 0.f));
        a[1][jj] = (short)f2bf(fmaxf(mx[8 + jj] + o1v[c1], 0.f));
    }

    short8 bfrag[4][2];
    #pragma unroll
    for (int t = 0; t < 4; ++t)
        #pragma unroll
        for (int ks = 0; ks < 2; ++ks)
            bfrag[t][ks] = *(const short8*)(cwb + ((size_t)(t * 2 + ks) * 64 + lane) * 8);

    f32x4 acc[4];
    #pragma unroll
    for (int t = 0; t < 4; ++t) acc[t] = (f32x4){0.f, 0.f, 0.f, 0.f};
    #pragma unroll
    for (int t = 0; t < 4; ++t) {
        acc[t] = __builtin_amdgcn_mfma_f32_16x16x32_bf16(a[0], bfrag[t][0], acc[t], 0, 0, 0);
        acc[t] = __builtin_amdgcn_mfma_f32_16x16x32_bf16(a[1], bfrag[t][1], acc[t], 0, 0, 0);
    }

    float sc[4], sh[4];
    #pragma unroll
    for (int t = 0; t < 4; ++t) {
        int n = t * 16 + m;
        sc[t] = scv[n];
        sh[t] = shv[n];
    }
    #pragma unroll
    for (int r = 0; r < 4; ++r) {
        int cv = __shfl(ci, grp * 4 + r);     // cnt of row v0+grp*4+r
        if (cv > 0) {
            unsigned short* op = grid + (size_t)(v0 + grp * 4 + r) * C_;
            #pragma unroll
            for (int t = 0; t < 4; ++t) {
                float val = fmaxf(acc[t][r] * sc[t] + sh[t], 0.f);
                op[t * 16 + m] = f2bf(val);
            }
        }
    }
}

// ---------------- Stage 5: bilinear gather, lane-split: 4 pts x 16 lanes x 4 ch -------
// quarter q = lane>>4 owns point p0+it*4+q; lane handles channels 4*(lane&15)..+3.
// Uniform math amortized 4x; all loads independent; branchless cnt-select.
__global__ __launch_bounds__(256) void k_gather16(
    const unsigned short* __restrict__ grid,   // bf16, occupied rows only
    const int* __restrict__ cnt,
    const float* __restrict__ vxyz,
    const float* __restrict__ shv,
    float* __restrict__ out)                   // f32 output
{
    int lane = threadIdx.x & 63;
    int q    = lane >> 4;                       // point-within-quad
    int ch   = (lane & 15) * 4;                 // 4 channels per lane
    int gw   = (blockIdx.x * 256 + threadIdx.x) >> 6;
    int p0   = gw * 16;                         // NPT_ % 16 == 0
    if (p0 >= NPT_) return;

    // empty-corner constant for this lane's 4 channels (f32 path == reference)
    f32x4 cstv = *(const f32x4*)(shv + ch);
    #pragma unroll
    for (int j = 0; j < 4; ++j) cstv[j] = fmaxf(cstv[j], 0.f);

    #pragma unroll
    for (int it = 0; it < 4; ++it) {
        int pt = p0 + it * 4 + q;
        int b  = pt / P_;
        float xq = vxyz[(size_t)pt * 3 + 0];
        float yq = vxyz[(size_t)pt * 3 + 1];
        int x0 = (int)floorf(xq); x0 = min(max(x0, 0), W_ - 1);
        int x1 = min(x0 + 1, W_ - 1);
        int y0 = (int)floorf(yq); y0 = min(max(y0, 0), H_ - 1);
        int y1 = min(y0 + 1, H_ - 1);
        float x0f = (float)x0, x1f = (float)x1, y0f = (float)y0, y1f = (float)y1;
        float wa = (x1f - xq) * (y1f - yq);
        float wb = (x1f - xq) * (yq - y0f);
        float wc = (xq - x0f) * (y1f - yq);
        float wd = (xq - x0f) * (yq - y0f);

        int ia = y0 * W_ + x0, ib = y1 * W_ + x0, ic = y0 * W_ + x1, id = y1 * W_ + x1;
        const int* cb = cnt + (size_t)b * S_;
        const unsigned short* g = grid + (size_t)b * S_ * C_ + ch;

        // independent loads: 4 x dwordx2 rows + 4 cnt words
        uint2 Ra = *(const uint2*)(g + (size_t)ia * C_);
        uint2 Rb = *(const uint2*)(g + (size_t)ib * C_);
        uint2 Rc = *(const uint2*)(g + (size_t)ic * C_);
        uint2 Rd = *(const uint2*)(g + (size_t)id * C_);
        int ca = cb[ia], cbn = cb[ib], cc = cb[ic], cd = cb[id];

        float A0,A1,A2,A3, B0,B1,B2,B3, C0,C1,C2,C3, D0,D1,D2,D3;
        bf2x(Ra.x, A0, A1); bf2x(Ra.y, A2, A3);
        bf2x(Rb.x, B0, B1); bf2x(Rb.y, B2, B3);
        bf2x(Rc.x, C0, C1); bf2x(Rc.y, C2, C3);
        bf2x(Rd.x, D0, D1); bf2x(Rd.y, D2, D3);

        bool oa = ca > 0, ob = cbn > 0, oc = cc > 0, od = cd > 0;
        f32x4 res;
        res[0] = wa * (oa ? A0 : cstv[0]) + wb * (ob ? B0 : cstv[0])
               + wc * (oc ? C0 : cstv[0]) + wd * (od ? D0 : cstv[0]);
        res[1] = wa * (oa ? A1 : cstv[1]) + wb * (ob ? B1 : cstv[1])
               + wc * (oc ? C1 : cstv[1]) + wd * (od ? D1 : cstv[1]);
        res[2] = wa * (oa ? A2 : cstv[2]) + wb * (ob ? B2 : cstv[2])
               + wc * (oc ? C2 : cstv[2]) + wd * (od ? D2 : cstv[2]);
        res[3] = wa * (oa ? A3 : cstv[3]) + wb * (ob ? B3 : cstv[3])
               + wc * (oc ? C3 : cstv[3]) + wd * (od ? D3 : cstv[3]);

        *(f32x4*)(out + (size_t)pt * C_ + ch) = res;
    }
}

extern "C" void kernel_launch(void* const* d_in, const int* in_sizes, int n_in,
                              void* d_out, int out_size, void* d_ws, size_t ws_size,
                              hipStream_t stream)
{
    const float* feat     = (const float*)d_in[1];
    const int*   indices  = (const int*)d_in[3];
    const int*   paddings = (const int*)d_in[4];
    const float* vxyz     = (const float*)d_in[5];
    const float* w_pn     = (const float*)d_in[6];
    const float* g1       = (const float*)d_in[7];
    const float* b1       = (const float*)d_in[8];
    const float* m1       = (const float*)d_in[9];
    const float* v1       = (const float*)d_in[10];
    const float* cw       = (const float*)d_in[11];
    const float* g2       = (const float*)d_in[12];
    const float* b2       = (const float*)d_in[13];
    const float* m2       = (const float*)d_in[14];
    const float* v2       = (const float*)d_in[15];

    // ws layout: grid 67.1MB | zs 25.6MB | cnt 2MB | gcursor 16B | off 2MB | cur 2MB |
    //            cwb 8KB | wpb 4KB | o1v/scv/shv 3x256B
    char* p = (char*)d_ws;
    unsigned short* grid = (unsigned short*)p;  p += (size_t)NVOX_ * C_ * 2;
    unsigned short* zs   = (unsigned short*)p;  p += (size_t)NPT_ * C_ * 2;
    int* cnt  = (int*)p;  p += (size_t)NVOX_ * 4;
    int* gcur = (int*)p;  p += 16;
    int* off  = (int*)p;  p += (size_t)NVOX_ * 4;
    int* cur  = (int*)p;  p += (size_t)NVOX_ * 4;
    unsigned short* cwb = (unsigned short*)p;  p += 8 * 64 * 8 * 2;
    unsigned short* wpb = (unsigned short*)p;  p += 4 * 64 * 8 * 2;
    float* o1v = (float*)p;  p += 64 * 4;
    float* scv = (float*)p;  p += 64 * 4;
    float* shv = (float*)p;

    // cnt + gcursor cleared in ONE memset (adjacent)
    hipMemsetAsync(cnt, 0, (size_t)NVOX_ * 4 + 16, stream);

    k_hist<<<(NPT_ + 255) / 256, 256, 0, stream>>>(indices, paddings, cnt);

    k_offsets<<<513, 256, 0, stream>>>(cnt, off, cur, gcur,
        cw, w_pn, g1, b1, m1, v1, g2, b2, m2, v2,
        cwb, wpb, o1v, scv, shv);

    k_z<<<3125, 256, 0, stream>>>(feat, indices, paddings, wpb, cur, zs);

    k_redconv<<<8192, 256, 0, stream>>>(zs, cnt, off, o1v, cwb, scv, shv, grid);

    // NPT_/16 = 12500 waves -> 3125 blocks
    k_gather16<<<3125, 256, 0, stream>>>(grid, cnt, vxyz, shv, (float*)d_out);
}

// Round 15
// 100.652 us; speedup vs baseline: 1.1739x; 1.0151x over previous
//
#include <hip/hip_runtime.h>
#include <hip/hip_bf16.h>

#define B_ 2
#define P_ 100000
#define CIN_ 23
#define C_ 64
#define H_ 512
#define W_ 512
#define S_ (H_*W_)       // 262144
#define NPT_ (B_*P_)     // 200000
#define NVOX_ (B_*S_)    // 524288

typedef __attribute__((ext_vector_type(8))) short short8;
typedef __attribute__((ext_vector_type(4))) float f32x4;
typedef __attribute__((ext_vector_type(4))) int i32x4;
// 4B-aligned f32x4 (feat rows are 92B -> only dword-aligned)
typedef __attribute__((ext_vector_type(4), aligned(4))) float f32x4u;

__device__ inline unsigned short f2bf(float f) {
    union { __hip_bfloat16 h; unsigned short u; } cv;
    cv.h = __float2bfloat16(f);
    return cv.u;
}
__device__ inline float bf2f(unsigned short u) {
    union { unsigned int i; float f; } cv;
    cv.i = ((unsigned int)u) << 16;
    return cv.f;
}
// expand packed 2xbf16 word -> two floats (1 VALU op each)
__device__ inline void bf2x(unsigned int u, float& lo, float& hi) {
    union { unsigned int i; float f; } a, b;
    a.i = u << 16;
    b.i = u & 0xffff0000u;
    lo = a.f; hi = b.f;
}

// ---------------- Stage 1: histogram ----------------
__global__ __launch_bounds__(256) void k_hist(
    const int* __restrict__ indices,
    const int* __restrict__ paddings,
    int* __restrict__ cnt)
{
    int pt = blockIdx.x * 256 + threadIdx.x;
    if (pt >= NPT_) return;
    if (paddings[pt] != 0) return;
    int v = (pt / P_) * S_ + indices[pt];
    atomicAdd(&cnt[v], 1);
}

// ---------------- Stage 2: exclusive-scan offsets + (block 512) param prep ----------
__global__ __launch_bounds__(256) void k_offsets(
    const int* __restrict__ cnt,
    int* __restrict__ off,
    int* __restrict__ cur,
    int* __restrict__ gcursor,
    const float* __restrict__ conv_w,
    const float* __restrict__ w_pn,
    const float* __restrict__ g1, const float* __restrict__ b1,
    const float* __restrict__ m1, const float* __restrict__ v1,
    const float* __restrict__ g2, const float* __restrict__ b2,
    const float* __restrict__ m2, const float* __restrict__ v2,
    unsigned short* __restrict__ cwb,   // [8][64][8] bf16 conv-W fragments
    unsigned short* __restrict__ wpb,   // [4][64][8] bf16 (w_pn * s1) fragments
    float* __restrict__ o1v,
    float* __restrict__ scv, float* __restrict__ shv)
{
    if (blockIdx.x >= 512) {            // ---- prep block ----
        int t = threadIdx.x;
        if (t < 64) {
            float s = g1[t] * rsqrtf(v1[t] + 1e-5f);
            o1v[t] = b1[t] - m1[t] * s;
            float s2 = g2[t] * rsqrtf(v2[t] + 1e-3f);
            scv[t] = s2;
            shv[t] = b2[t] - m2[t] * s2;
        }
        #pragma unroll
        for (int e = 0; e < 16; ++e) {
            int idx  = t * 16 + e;              // 0..4095
            int f    = idx >> 9;                // 0..7
            int lane = (idx >> 3) & 63;
            int j    = idx & 7;
            int tq = f >> 1, ks = f & 1;
            int row = lane & 15, grp = lane >> 4;
            cwb[idx] = f2bf(conv_w[(tq * 16 + row) * 64 + ks * 32 + grp * 8 + j]);
        }
        #pragma unroll
        for (int e = 0; e < 8; ++e) {
            int idx  = t * 8 + e;               // 0..2047
            int tq   = idx >> 9;                // 0..3
            int lane = (idx >> 3) & 63;
            int j    = idx & 7;
            int row = lane & 15, grp = lane >> 4;
            int n = tq * 16 + row;
            int k = grp * 8 + j;
            // fold BN1 scale (s1[n] > 0): max(z*s1) == max(z)*s1
            float s1n = g1[n] * rsqrtf(v1[n] + 1e-5f);
            wpb[idx] = (k < CIN_) ? f2bf(w_pn[k * C_ + n] * s1n) : 0;
        }
        return;
    }

    __shared__ int lds[256];
    __shared__ int sbase;
    int tid  = threadIdx.x;
    int base = blockIdx.x * 1024 + tid * 4;
    i32x4 c = *(const i32x4*)(cnt + base);
    int s1 = c[0] + c[1], s2 = s1 + c[2], s3 = s2 + c[3];
    lds[tid] = s3;
    __syncthreads();
    #pragma unroll
    for (int d = 1; d < 256; d <<= 1) {
        int v = (tid >= d) ? lds[tid - d] : 0;
        __syncthreads();
        if (tid >= d) lds[tid] += v;
        __syncthreads();
    }
    if (tid == 0) sbase = atomicAdd(gcursor, lds[255]);
    __syncthreads();
    int o = sbase + (tid == 0 ? 0 : lds[tid - 1]);
    i32x4 e;
    e[0] = o; e[1] = o + c[0]; e[2] = o + s1; e[3] = o + s2;
    *(i32x4*)(off + base) = e;
    *(i32x4*)(cur + base) = e;
}

// ---------------- Stage 3: z = feat @ (w_pn*s1) via MFMA -> voxel-sorted zs ----------
__global__ __launch_bounds__(256) void k_z(
    const float* __restrict__ feat,
    const int* __restrict__ indices,
    const int* __restrict__ paddings,
    const unsigned short* __restrict__ wpb,   // [4][64][8]
    int* __restrict__ cur,
    unsigned short* __restrict__ zs)          // bf16 [NPT_][C_] voxel-sorted
{
    int lane = threadIdx.x & 63;
    int wid  = (blockIdx.x * 256 + threadIdx.x) >> 6;
    int p0   = wid * 16;                      // NPT_ % 16 == 0
    int row  = lane & 15;
    int grp  = lane >> 4;

    int slot = -1;
    if (lane < 16) {
        int pt = p0 + lane;
        if (paddings[pt] == 0) {
            int v = (pt / P_) * S_ + indices[pt];
            slot = atomicAdd(&cur[v], 1);
        }
    }

    // A fragment via two 4B-aligned vector loads (grp 3 = all k>=24 -> zero)
    const float* f = feat + (size_t)(p0 + row) * CIN_;
    short8 a = (short8){0, 0, 0, 0, 0, 0, 0, 0};
    if (grp < 3) {
        f32x4u v0 = *(const f32x4u*)(f + grp * 8);
        f32x4u v1 = *(const f32x4u*)(f + grp * 8 + 4);   // grp2,j=3 reads f[23]: masked below
        #pragma unroll
        for (int j = 0; j < 4; ++j) {
            int k0 = grp * 8 + j;
            int k1 = grp * 8 + 4 + j;
            a[j]     = (short)(k0 < CIN_ ? f2bf(v0[j]) : 0);
            a[j + 4] = (short)(k1 < CIN_ ? f2bf(v1[j]) : 0);
        }
    }

    short8 bfrag[4];
    #pragma unroll
    for (int t = 0; t < 4; ++t)
        bfrag[t] = *(const short8*)(wpb + ((size_t)t * 64 + lane) * 8);

    f32x4 acc[4];
    #pragma unroll
    for (int t = 0; t < 4; ++t) acc[t] = (f32x4){0.f, 0.f, 0.f, 0.f};
    #pragma unroll
    for (int t = 0; t < 4; ++t)
        acc[t] = __builtin_amdgcn_mfma_f32_16x16x32_bf16(a, bfrag[t], acc[t], 0, 0, 0);

    #pragma unroll
    for (int r = 0; r < 4; ++r) {
        int sm = __shfl(slot, grp * 4 + r);
        if (sm >= 0) {
            unsigned short* op = zs + (size_t)sm * C_;
            #pragma unroll
            for (int t = 0; t < 4; ++t)
                op[t * 16 + row] = f2bf(acc[t][r]);
        }
    }
}

// ---------------- Stage 4: FUSED reduce-max + BN1-off + ReLU + 1x1conv + BN2 + ReLU --
// one wave = 16 voxels; segment loop unrolled x2 (4 b128 loads in flight / iter);
// stores ONLY occupied rows
__global__ __launch_bounds__(256) void k_redconv(
    const unsigned short* __restrict__ zs,
    const int* __restrict__ cnt,
    const int* __restrict__ off,
    const float* __restrict__ o1v,
    const unsigned short* __restrict__ cwb,   // [8][64][8]
    const float* __restrict__ scv, const float* __restrict__ shv,
    unsigned short* __restrict__ grid)        // bf16 [NVOX_][C_], occupied rows only
{
    int lane = threadIdx.x & 63;
    int wid  = (blockIdx.x * 256 + threadIdx.x) >> 6;
    int v0   = wid * 16;                      // NVOX_/16 waves exactly
    int m    = lane & 15;
    int grp  = lane >> 4;

    int vi = v0 + m;
    int ci = cnt[vi];
    if (__all(ci == 0)) return;               // all 16 voxels empty (~0.4%)
    int oi = off[vi];

    float mx[16];
    #pragma unroll
    for (int i = 0; i < 16; ++i) mx[i] = -1e30f;

    for (int j = 0; ; j += 2) {
        bool l0 = j < ci, l1 = (j + 1) < ci;  // l1 => l0
        if (!__any(l0)) break;
        const unsigned short* zr0 = zs + (size_t)(oi + (l0 ? j : 0)) * C_ + grp * 8;
        const unsigned short* zr1 = zs + (size_t)(oi + (l1 ? j + 1 : 0)) * C_ + grp * 8;
        short8 lo0 = *(const short8*)(zr0);
        short8 hi0 = *(const short8*)(zr0 + 32);
        short8 lo1 = *(const short8*)(zr1);
        short8 hi1 = *(const short8*)(zr1 + 32);
        if (l0) {
            #pragma unroll
            for (int jj = 0; jj < 8; ++jj) {
                mx[jj]     = fmaxf(mx[jj],     bf2f((unsigned short)lo0[jj]));
                mx[8 + jj] = fmaxf(mx[8 + jj], bf2f((unsigned short)hi0[jj]));
            }
        }
        if (l1) {
            #pragma unroll
            for (int jj = 0; jj < 8; ++jj) {
                mx[jj]     = fmaxf(mx[jj],     bf2f((unsigned short)lo1[jj]));
                mx[8 + jj] = fmaxf(mx[8 + jj], bf2f((unsigned short)hi1[jj]));
            }
        }
    }

    // + BN1 offset + ReLU -> A fragments (empty voxel: -1e30 -> relu -> 0 exactly)
    short8 a[2];
    #pragma unroll
    for (int jj = 0; jj < 8; ++jj) {
        int c0 = grp * 8 + jj;
        int c1 = 32 + grp * 8 + jj;
        a[0][jj] = (short)f2bf(fmaxf(mx[jj]     + o1v[c0], 0.f));
        a[1][jj] = (short)f2bf(fmaxf(mx[8 + jj] + o1v[c1], 0.f));
    }

    short8 bfrag[4][2];
    #pragma unroll
    for (int t = 0; t < 4; ++t)
        #pragma unroll
        for (int ks = 0; ks < 2; ++ks)
            bfrag[t][ks] = *(const short8*)(cwb + ((size_t)(t * 2 + ks) * 64 + lane) * 8);

    f32x4 acc[4];
    #pragma unroll
    for (int t = 0; t < 4; ++t) acc[t] = (f32x4){0.f, 0.f, 0.f, 0.f};
    #pragma unroll
    for (int t = 0; t < 4; ++t) {
        acc[t] = __builtin_amdgcn_mfma_f32_16x16x32_bf16(a[0], bfrag[t][0], acc[t], 0, 0, 0);
        acc[t] = __builtin_amdgcn_mfma_f32_16x16x32_bf16(a[1], bfrag[t][1], acc[t], 0, 0, 0);
    }

    float sc[4], sh[4];
    #pragma unroll
    for (int t = 0; t < 4; ++t) {
        int n = t * 16 + m;
        sc[t] = scv[n];
        sh[t] = shv[n];
    }
    #pragma unroll
    for (int r = 0; r < 4; ++r) {
        int cv = __shfl(ci, grp * 4 + r);     // cnt of row v0+grp*4+r
        if (cv > 0) {
            unsigned short* op = grid + (size_t)(v0 + grp * 4 + r) * C_;
            #pragma unroll
            for (int t = 0; t < 4; ++t) {
                float val = fmaxf(acc[t][r] * sc[t] + sh[t], 0.f);
                op[t * 16 + m] = f2bf(val);
            }
        }
    }
}

// ---------------- Stage 5: bilinear gather, 32 pts/wave lane-split ----------
// quarter q = lane>>4 owns point p0+it*4+q (it<8); lane handles 4 channels.
// All loads independent; branchless cnt-select.
__global__ __launch_bounds__(256) void k_gather32(
    const unsigned short* __restrict__ grid,   // bf16, occupied rows only
    const int* __restrict__ cnt,
    const float* __restrict__ vxyz,
    const float* __restrict__ shv,
    float* __restrict__ out)                   // f32 output
{
    int lane = threadIdx.x & 63;
    int q    = lane >> 4;                       // point-within-quad
    int ch   = (lane & 15) * 4;                 // 4 channels per lane
    int gw   = (blockIdx.x * 256 + threadIdx.x) >> 6;
    int p0   = gw * 32;
    if (p0 >= NPT_) return;                     // NPT_ % 32 == 0

    // empty-corner constant for this lane's 4 channels (f32 path == reference)
    f32x4 cstv = *(const f32x4*)(shv + ch);
    #pragma unroll
    for (int j = 0; j < 4; ++j) cstv[j] = fmaxf(cstv[j], 0.f);

    #pragma unroll
    for (int it = 0; it < 8; ++it) {
        int pt = p0 + it * 4 + q;
        int b  = pt / P_;
        float xq = vxyz[(size_t)pt * 3 + 0];
        float yq = vxyz[(size_t)pt * 3 + 1];
        int x0 = (int)floorf(xq); x0 = min(max(x0, 0), W_ - 1);
        int x1 = min(x0 + 1, W_ - 1);
        int y0 = (int)floorf(yq); y0 = min(max(y0, 0), H_ - 1);
        int y1 = min(y0 + 1, H_ - 1);
        float x0f = (float)x0, x1f = (float)x1, y0f = (float)y0, y1f = (float)y1;
        float wa = (x1f - xq) * (y1f - yq);
        float wb = (x1f - xq) * (yq - y0f);
        float wc = (xq - x0f) * (y1f - yq);
        float wd = (xq - x0f) * (yq - y0f);

        int ia = y0 * W_ + x0, ib = y1 * W_ + x0, ic = y0 * W_ + x1, id = y1 * W_ + x1;
        const int* cb = cnt + (size_t)b * S_;
        const unsigned short* g = grid + (size_t)b * S_ * C_ + ch;

        // independent loads: 4 x dwordx2 rows + 4 cnt words
        uint2 Ra = *(const uint2*)(g + (size_t)ia * C_);
        uint2 Rb = *(const uint2*)(g + (size_t)ib * C_);
        uint2 Rc = *(const uint2*)(g + (size_t)ic * C_);
        uint2 Rd = *(const uint2*)(g + (size_t)id * C_);
        int ca = cb[ia], cbn = cb[ib], cc = cb[ic], cd = cb[id];

        float A0,A1,A2,A3, B0,B1,B2,B3, C0,C1,C2,C3, D0,D1,D2,D3;
        bf2x(Ra.x, A0, A1); bf2x(Ra.y, A2, A3);
        bf2x(Rb.x, B0, B1); bf2x(Rb.y, B2, B3);
        bf2x(Rc.x, C0, C1); bf2x(Rc.y, C2, C3);
        bf2x(Rd.x, D0, D1); bf2x(Rd.y, D2, D3);

        bool oa = ca > 0, ob = cbn > 0, oc = cc > 0, od = cd > 0;
        f32x4 res;
        res[0] = wa * (oa ? A0 : cstv[0]) + wb * (ob ? B0 : cstv[0])
               + wc * (oc ? C0 : cstv[0]) + wd * (od ? D0 : cstv[0]);
        res[1] = wa * (oa ? A1 : cstv[1]) + wb * (ob ? B1 : cstv[1])
               + wc * (oc ? C1 : cstv[1]) + wd * (od ? D1 : cstv[1]);
        res[2] = wa * (oa ? A2 : cstv[2]) + wb * (ob ? B2 : cstv[2])
               + wc * (oc ? C2 : cstv[2]) + wd * (od ? D2 : cstv[2]);
        res[3] = wa * (oa ? A3 : cstv[3]) + wb * (ob ? B3 : cstv[3])
               + wc * (oc ? C3 : cstv[3]) + wd * (od ? D3 : cstv[3]);

        *(f32x4*)(out + (size_t)pt * C_ + ch) = res;
    }
}

extern "C" void kernel_launch(void* const* d_in, const int* in_sizes, int n_in,
                              void* d_out, int out_size, void* d_ws, size_t ws_size,
                              hipStream_t stream)
{
    const float* feat     = (const float*)d_in[1];
    const int*   indices  = (const int*)d_in[3];
    const int*   paddings = (const int*)d_in[4];
    const float* vxyz     = (const float*)d_in[5];
    const float* w_pn     = (const float*)d_in[6];
    const float* g1       = (const float*)d_in[7];
    const float* b1       = (const float*)d_in[8];
    const float* m1       = (const float*)d_in[9];
    const float* v1       = (const float*)d_in[10];
    const float* cw       = (const float*)d_in[11];
    const float* g2       = (const float*)d_in[12];
    const float* b2       = (const float*)d_in[13];
    const float* m2       = (const float*)d_in[14];
    const float* v2       = (const float*)d_in[15];

    // ws layout: grid 67.1MB | zs 25.6MB | cnt 2MB | gcursor 16B | off 2MB | cur 2MB |
    //            cwb 8KB | wpb 4KB | o1v/scv/shv 3x256B
    char* p = (char*)d_ws;
    unsigned short* grid = (unsigned short*)p;  p += (size_t)NVOX_ * C_ * 2;
    unsigned short* zs   = (unsigned short*)p;  p += (size_t)NPT_ * C_ * 2;
    int* cnt  = (int*)p;  p += (size_t)NVOX_ * 4;
    int* gcur = (int*)p;  p += 16;
    int* off  = (int*)p;  p += (size_t)NVOX_ * 4;
    int* cur  = (int*)p;  p += (size_t)NVOX_ * 4;
    unsigned short* cwb = (unsigned short*)p;  p += 8 * 64 * 8 * 2;
    unsigned short* wpb = (unsigned short*)p;  p += 4 * 64 * 8 * 2;
    float* o1v = (float*)p;  p += 64 * 4;
    float* scv = (float*)p;  p += 64 * 4;
    float* shv = (float*)p;

    // cnt + gcursor cleared in ONE memset (adjacent)
    hipMemsetAsync(cnt, 0, (size_t)NVOX_ * 4 + 16, stream);

    k_hist<<<(NPT_ + 255) / 256, 256, 0, stream>>>(indices, paddings, cnt);

    k_offsets<<<513, 256, 0, stream>>>(cnt, off, cur, gcur,
        cw, w_pn, g1, b1, m1, v1, g2, b2, m2, v2,
        cwb, wpb, o1v, scv, shv);

    k_z<<<3125, 256, 0, stream>>>(feat, indices, paddings, wpb, cur, zs);

    k_redconv<<<8192, 256, 0, stream>>>(zs, cnt, off, o1v, cwb, scv, shv, grid);

    // NPT_/32 = 6250 waves -> 1563 blocks (last 2 waves idle)
    k_gather32<<<1563, 256, 0, stream>>>(grid, cnt, vxyz, shv, (float*)d_out);
}

// Round 16
// 96.990 us; speedup vs baseline: 1.2182x; 1.0378x over previous
//
#include <hip/hip_runtime.h>
#include <hip/hip_bf16.h>

#define B_ 2
#define P_ 100000
#define CIN_ 23
#define C_ 64
#define H_ 512
#define W_ 512
#define S_ (H_*W_)       // 262144
#define NPT_ (B_*P_)     // 200000
#define NVOX_ (B_*S_)    // 524288

typedef __attribute__((ext_vector_type(8))) short short8;
typedef __attribute__((ext_vector_type(4))) float f32x4;
typedef __attribute__((ext_vector_type(4))) int i32x4;
// 4B-aligned f32x4 (feat rows are 92B -> only dword-aligned)
typedef __attribute__((ext_vector_type(4), aligned(4))) float f32x4u;

__device__ inline unsigned short f2bf(float f) {
    union { __hip_bfloat16 h; unsigned short u; } cv;
    cv.h = __float2bfloat16(f);
    return cv.u;
}
__device__ inline float bf2f(unsigned short u) {
    union { unsigned int i; float f; } cv;
    cv.i = ((unsigned int)u) << 16;
    return cv.f;
}
// expand packed 2xbf16 word -> two floats (1 VALU op each)
__device__ inline void bf2x(unsigned int u, float& lo, float& hi) {
    union { unsigned int i; float f; } a, b;
    a.i = u << 16;
    b.i = u & 0xffff0000u;
    lo = a.f; hi = b.f;
}

// ---------------- Stage 1: histogram ----------------
__global__ __launch_bounds__(256) void k_hist(
    const int* __restrict__ indices,
    const int* __restrict__ paddings,
    int* __restrict__ cnt)
{
    int pt = blockIdx.x * 256 + threadIdx.x;
    if (pt >= NPT_) return;
    if (paddings[pt] != 0) return;
    int v = (pt / P_) * S_ + indices[pt];
    atomicAdd(&cnt[v], 1);
}

// ---------------- Stage 2: DUAL exclusive scan (point-slots + occupied-row ids)
//                  + (block 512) param prep ----------
__global__ __launch_bounds__(256) void k_offsets(
    const int* __restrict__ cnt,
    int* __restrict__ off,
    int* __restrict__ cur,
    int* __restrict__ rid,              // compact row id, -1 if empty
    int* __restrict__ gcursor,          // [0]=point cursor [1]=row cursor
    const float* __restrict__ conv_w,
    const float* __restrict__ w_pn,
    const float* __restrict__ g1, const float* __restrict__ b1,
    const float* __restrict__ m1, const float* __restrict__ v1,
    const float* __restrict__ g2, const float* __restrict__ b2,
    const float* __restrict__ m2, const float* __restrict__ v2,
    unsigned short* __restrict__ cwb,   // [8][64][8] bf16 conv-W fragments
    unsigned short* __restrict__ wpb,   // [4][64][8] bf16 (w_pn * s1) fragments
    float* __restrict__ o1v,
    float* __restrict__ scv, float* __restrict__ shv)
{
    if (blockIdx.x >= 512) {            // ---- prep block ----
        int t = threadIdx.x;
        if (t < 64) {
            float s = g1[t] * rsqrtf(v1[t] + 1e-5f);
            o1v[t] = b1[t] - m1[t] * s;
            float s2 = g2[t] * rsqrtf(v2[t] + 1e-3f);
            scv[t] = s2;
            shv[t] = b2[t] - m2[t] * s2;
        }
        #pragma unroll
        for (int e = 0; e < 16; ++e) {
            int idx  = t * 16 + e;              // 0..4095
            int f    = idx >> 9;                // 0..7
            int lane = (idx >> 3) & 63;
            int j    = idx & 7;
            int tq = f >> 1, ks = f & 1;
            int row = lane & 15, grp = lane >> 4;
            cwb[idx] = f2bf(conv_w[(tq * 16 + row) * 64 + ks * 32 + grp * 8 + j]);
        }
        #pragma unroll
        for (int e = 0; e < 8; ++e) {
            int idx  = t * 8 + e;               // 0..2047
            int tq   = idx >> 9;                // 0..3
            int lane = (idx >> 3) & 63;
            int j    = idx & 7;
            int row = lane & 15, grp = lane >> 4;
            int n = tq * 16 + row;
            int k = grp * 8 + j;
            // fold BN1 scale (s1[n] > 0): max(z*s1) == max(z)*s1
            float s1n = g1[n] * rsqrtf(v1[n] + 1e-5f);
            wpb[idx] = (k < CIN_) ? f2bf(w_pn[k * C_ + n] * s1n) : 0;
        }
        return;
    }

    __shared__ int lds_c[256], lds_o[256];
    __shared__ int sbase_c, sbase_o;
    int tid  = threadIdx.x;
    int base = blockIdx.x * 1024 + tid * 4;
    i32x4 c = *(const i32x4*)(cnt + base);
    int o0 = c[0] > 0, o1 = c[1] > 0, o2 = c[2] > 0, o3 = c[3] > 0;
    int sc1 = c[0] + c[1], sc2 = sc1 + c[2], sc3 = sc2 + c[3];
    int so1 = o0 + o1,     so2 = so1 + o2,   so3 = so2 + o3;
    lds_c[tid] = sc3;
    lds_o[tid] = so3;
    __syncthreads();
    #pragma unroll
    for (int d = 1; d < 256; d <<= 1) {
        int vc = (tid >= d) ? lds_c[tid - d] : 0;
        int vo = (tid >= d) ? lds_o[tid - d] : 0;
        __syncthreads();
        if (tid >= d) { lds_c[tid] += vc; lds_o[tid] += vo; }
        __syncthreads();
    }
    if (tid == 0) {
        sbase_c = atomicAdd(&gcursor[0], lds_c[255]);
        sbase_o = atomicAdd(&gcursor[1], lds_o[255]);
    }
    __syncthreads();
    int oc = sbase_c + (tid == 0 ? 0 : lds_c[tid - 1]);
    int oo = sbase_o + (tid == 0 ? 0 : lds_o[tid - 1]);
    i32x4 e, ridv;
    e[0] = oc; e[1] = oc + c[0]; e[2] = oc + sc1; e[3] = oc + sc2;
    ridv[0] = o0 ? oo       : -1;
    ridv[1] = o1 ? oo + so1 - o1 : -1;   // oo + prefix before elem1 = oo + o0
    ridv[2] = o2 ? oo + so2 - o2 : -1;   // oo + o0 + o1
    ridv[3] = o3 ? oo + so3 - o3 : -1;   // oo + o0 + o1 + o2
    *(i32x4*)(off + base) = e;
    *(i32x4*)(cur + base) = e;
    *(i32x4*)(rid + base) = ridv;
}

// ---------------- Stage 3: z = feat @ (w_pn*s1) via MFMA -> voxel-sorted zs ----------
__global__ __launch_bounds__(256) void k_z(
    const float* __restrict__ feat,
    const int* __restrict__ indices,
    const int* __restrict__ paddings,
    const unsigned short* __restrict__ wpb,   // [4][64][8]
    int* __restrict__ cur,
    unsigned short* __restrict__ zs)          // bf16 [NPT_][C_] voxel-sorted
{
    int lane = threadIdx.x & 63;
    int wid  = (blockIdx.x * 256 + threadIdx.x) >> 6;
    int p0   = wid * 16;                      // NPT_ % 16 == 0
    int row  = lane & 15;
    int grp  = lane >> 4;

    int slot = -1;
    if (lane < 16) {
        int pt = p0 + lane;
        if (paddings[pt] == 0) {
            int v = (pt / P_) * S_ + indices[pt];
            slot = atomicAdd(&cur[v], 1);
        }
    }

    // A fragment via two 4B-aligned vector loads (grp 3 = all k>=24 -> zero)
    const float* f = feat + (size_t)(p0 + row) * CIN_;
    short8 a = (short8){0, 0, 0, 0, 0, 0, 0, 0};
    if (grp < 3) {
        f32x4u v0 = *(const f32x4u*)(f + grp * 8);
        f32x4u v1 = *(const f32x4u*)(f + grp * 8 + 4);
        #pragma unroll
        for (int j = 0; j < 4; ++j) {
            int k0 = grp * 8 + j;
            int k1 = grp * 8 + 4 + j;
            a[j]     = (short)(k0 < CIN_ ? f2bf(v0[j]) : 0);
            a[j + 4] = (short)(k1 < CIN_ ? f2bf(v1[j]) : 0);
        }
    }

    short8 bfrag[4];
    #pragma unroll
    for (int t = 0; t < 4; ++t)
        bfrag[t] = *(const short8*)(wpb + ((size_t)t * 64 + lane) * 8);

    f32x4 acc[4];
    #pragma unroll
    for (int t = 0; t < 4; ++t) acc[t] = (f32x4){0.f, 0.f, 0.f, 0.f};
    #pragma unroll
    for (int t = 0; t < 4; ++t)
        acc[t] = __builtin_amdgcn_mfma_f32_16x16x32_bf16(a, bfrag[t], acc[t], 0, 0, 0);

    #pragma unroll
    for (int r = 0; r < 4; ++r) {
        int sm = __shfl(slot, grp * 4 + r);
        if (sm >= 0) {
            unsigned short* op = zs + (size_t)sm * C_;
            #pragma unroll
            for (int t = 0; t < 4; ++t)
                op[t * 16 + row] = f2bf(acc[t][r]);
        }
    }
}

// ---------------- Stage 4: FUSED reduce-max + BN1-off + ReLU + 1x1conv + BN2 + ReLU --
// one wave = 16 voxels; writes COMPACT rows grid_c[rid[v]] (contiguous, coalesced)
__global__ __launch_bounds__(256) void k_redconv(
    const unsigned short* __restrict__ zs,
    const int* __restrict__ cnt,
    const int* __restrict__ off,
    const int* __restrict__ rid,
    const float* __restrict__ o1v,
    const unsigned short* __restrict__ cwb,   // [8][64][8]
    const float* __restrict__ scv, const float* __restrict__ shv,
    unsigned short* __restrict__ grid_c)      // bf16 [nocc][C_] compact
{
    int lane = threadIdx.x & 63;
    int wid  = (blockIdx.x * 256 + threadIdx.x) >> 6;
    int v0   = wid * 16;                      // NVOX_/16 waves exactly
    int m    = lane & 15;
    int grp  = lane >> 4;

    int vi = v0 + m;
    int ci = cnt[vi];
    if (__all(ci == 0)) return;               // all 16 voxels empty (~0.4%)
    int oi = off[vi];
    int ri = rid[vi];

    float mx[16];
    #pragma unroll
    for (int i = 0; i < 16; ++i) mx[i] = -1e30f;

    for (int j = 0; ; j += 2) {
        bool l0 = j < ci, l1 = (j + 1) < ci;  // l1 => l0
        if (!__any(l0)) break;
        const unsigned short* zr0 = zs + (size_t)(oi + (l0 ? j : 0)) * C_ + grp * 8;
        const unsigned short* zr1 = zs + (size_t)(oi + (l1 ? j + 1 : 0)) * C_ + grp * 8;
        short8 lo0 = *(const short8*)(zr0);
        short8 hi0 = *(const short8*)(zr0 + 32);
        short8 lo1 = *(const short8*)(zr1);
        short8 hi1 = *(const short8*)(zr1 + 32);
        if (l0) {
            #pragma unroll
            for (int jj = 0; jj < 8; ++jj) {
                mx[jj]     = fmaxf(mx[jj],     bf2f((unsigned short)lo0[jj]));
                mx[8 + jj] = fmaxf(mx[8 + jj], bf2f((unsigned short)hi0[jj]));
            }
        }
        if (l1) {
            #pragma unroll
            for (int jj = 0; jj < 8; ++jj) {
                mx[jj]     = fmaxf(mx[jj],     bf2f((unsigned short)lo1[jj]));
                mx[8 + jj] = fmaxf(mx[8 + jj], bf2f((unsigned short)hi1[jj]));
            }
        }
    }

    // + BN1 offset + ReLU -> A fragments (empty voxel: -1e30 -> relu -> 0 exactly)
    short8 a[2];
    #pragma unroll
    for (int jj = 0; jj < 8; ++jj) {
        int c0 = grp * 8 + jj;
        int c1 = 32 + grp * 8 + jj;
        a[0][jj] = (short)f2bf(fmaxf(mx[jj]     + o1v[c0], 0.f));
        a[1][jj] = (short)f2bf(fmaxf(mx[8 + jj] + o1v[c1], 0.f));
    }

    short8 bfrag[4][2];
    #pragma unroll
    for (int t = 0; t < 4; ++t)
        #pragma unroll
        for (int ks = 0; ks < 2; ++ks)
            bfrag[t][ks] = *(const short8*)(cwb + ((size_t)(t * 2 + ks) * 64 + lane) * 8);

    f32x4 acc[4];
    #pragma unroll
    for (int t = 0; t < 4; ++t) acc[t] = (f32x4){0.f, 0.f, 0.f, 0.f};
    #pragma unroll
    for (int t = 0; t < 4; ++t) {
        acc[t] = __builtin_amdgcn_mfma_f32_16x16x32_bf16(a[0], bfrag[t][0], acc[t], 0, 0, 0);
        acc[t] = __builtin_amdgcn_mfma_f32_16x16x32_bf16(a[1], bfrag[t][1], acc[t], 0, 0, 0);
    }

    float sc[4], sh[4];
    #pragma unroll
    for (int t = 0; t < 4; ++t) {
        int n = t * 16 + m;
        sc[t] = scv[n];
        sh[t] = shv[n];
    }
    #pragma unroll
    for (int r = 0; r < 4; ++r) {
        int rv = __shfl(ri, grp * 4 + r);     // compact row id of voxel v0+grp*4+r
        if (rv >= 0) {
            unsigned short* op = grid_c + (size_t)rv * C_;
            #pragma unroll
            for (int t = 0; t < 4; ++t) {
                float val = fmaxf(acc[t][r] * sc[t] + sh[t], 0.f);
                op[t * 16 + m] = f2bf(val);
            }
        }
    }
}

// ---------------- Stage 5: bilinear gather, 32 pts/wave, compact rows via rid --------
// quarter q = lane>>4 owns point p0+it*4+q (it<8); lane handles 4 channels.
// rid load -> row load (2-level, branchless); rows drawn from ~19.5MB compact region.
__global__ __launch_bounds__(256) void k_gather32(
    const unsigned short* __restrict__ grid_c,  // bf16 compact rows
    const int* __restrict__ rid,
    const float* __restrict__ vxyz,
    const float* __restrict__ shv,
    float* __restrict__ out)                    // f32 output
{
    int lane = threadIdx.x & 63;
    int q    = lane >> 4;                       // point-within-quad
    int ch   = (lane & 15) * 4;                 // 4 channels per lane
    int gw   = (blockIdx.x * 256 + threadIdx.x) >> 6;
    int p0   = gw * 32;
    if (p0 >= NPT_) return;                     // NPT_ % 32 == 0

    // empty-corner constant for this lane's 4 channels (f32 path == reference)
    f32x4 cstv = *(const f32x4*)(shv + ch);
    #pragma unroll
    for (int j = 0; j < 4; ++j) cstv[j] = fmaxf(cstv[j], 0.f);

    const unsigned short* gc = grid_c + ch;

    #pragma unroll
    for (int it = 0; it < 8; ++it) {
        int pt = p0 + it * 4 + q;
        int b  = pt / P_;
        float xq = vxyz[(size_t)pt * 3 + 0];
        float yq = vxyz[(size_t)pt * 3 + 1];
        int x0 = (int)floorf(xq); x0 = min(max(x0, 0), W_ - 1);
        int x1 = min(x0 + 1, W_ - 1);
        int y0 = (int)floorf(yq); y0 = min(max(y0, 0), H_ - 1);
        int y1 = min(y0 + 1, H_ - 1);
        float x0f = (float)x0, x1f = (float)x1, y0f = (float)y0, y1f = (float)y1;
        float wa = (x1f - xq) * (y1f - yq);
        float wb = (x1f - xq) * (yq - y0f);
        float wc = (xq - x0f) * (y1f - yq);
        float wd = (xq - x0f) * (yq - y0f);

        int ia = y0 * W_ + x0, ib = y1 * W_ + x0, ic = y0 * W_ + x1, id = y1 * W_ + x1;
        const int* rb = rid + (size_t)b * S_;

        int ra = rb[ia], rbn = rb[ib], rc = rb[ic], rd = rb[id];
        uint2 Ra = *(const uint2*)(gc + (size_t)max(ra,  0) * C_);
        uint2 Rb = *(const uint2*)(gc + (size_t)max(rbn, 0) * C_);
        uint2 Rc = *(const uint2*)(gc + (size_t)max(rc,  0) * C_);
        uint2 Rd = *(const uint2*)(gc + (size_t)max(rd,  0) * C_);

        float A0,A1,A2,A3, B0,B1,B2,B3, C0,C1,C2,C3, D0,D1,D2,D3;
        bf2x(Ra.x, A0, A1); bf2x(Ra.y, A2, A3);
        bf2x(Rb.x, B0, B1); bf2x(Rb.y, B2, B3);
        bf2x(Rc.x, C0, C1); bf2x(Rc.y, C2, C3);
        bf2x(Rd.x, D0, D1); bf2x(Rd.y, D2, D3);

        bool oa = ra >= 0, ob = rbn >= 0, oc = rc >= 0, od = rd >= 0;
        f32x4 res;
        res[0] = wa * (oa ? A0 : cstv[0]) + wb * (ob ? B0 : cstv[0])
               + wc * (oc ? C0 : cstv[0]) + wd * (od ? D0 : cstv[0]);
        res[1] = wa * (oa ? A1 : cstv[1]) + wb * (ob ? B1 : cstv[1])
               + wc * (oc ? C1 : cstv[1]) + wd * (od ? D1 : cstv[1]);
        res[2] = wa * (oa ? A2 : cstv[2]) + wb * (ob ? B2 : cstv[2])
               + wc * (oc ? C2 : cstv[2]) + wd * (od ? D2 : cstv[2]);
        res[3] = wa * (oa ? A3 : cstv[3]) + wb * (ob ? B3 : cstv[3])
               + wc * (oc ? C3 : cstv[3]) + wd * (od ? D3 : cstv[3]);

        *(f32x4*)(out + (size_t)pt * C_ + ch) = res;
    }
}

extern "C" void kernel_launch(void* const* d_in, const int* in_sizes, int n_in,
                              void* d_out, int out_size, void* d_ws, size_t ws_size,
                              hipStream_t stream)
{
    const float* feat     = (const float*)d_in[1];
    const int*   indices  = (const int*)d_in[3];
    const int*   paddings = (const int*)d_in[4];
    const float* vxyz     = (const float*)d_in[5];
    const float* w_pn     = (const float*)d_in[6];
    const float* g1       = (const float*)d_in[7];
    const float* b1       = (const float*)d_in[8];
    const float* m1       = (const float*)d_in[9];
    const float* v1       = (const float*)d_in[10];
    const float* cw       = (const float*)d_in[11];
    const float* g2       = (const float*)d_in[12];
    const float* b2       = (const float*)d_in[13];
    const float* m2       = (const float*)d_in[14];
    const float* v2       = (const float*)d_in[15];

    // ws layout: grid_c 25.6MB | zs 25.6MB | cnt 2MB | gcursor 16B | off 2MB |
    //            cur 2MB | rid 2MB | cwb 8KB | wpb 4KB | o1v/scv/shv 3x256B
    char* p = (char*)d_ws;
    unsigned short* grid_c = (unsigned short*)p;  p += (size_t)NPT_ * C_ * 2;
    unsigned short* zs     = (unsigned short*)p;  p += (size_t)NPT_ * C_ * 2;
    int* cnt  = (int*)p;  p += (size_t)NVOX_ * 4;
    int* gcur = (int*)p;  p += 16;
    int* off  = (int*)p;  p += (size_t)NVOX_ * 4;
    int* cur  = (int*)p;  p += (size_t)NVOX_ * 4;
    int* rid  = (int*)p;  p += (size_t)NVOX_ * 4;
    unsigned short* cwb = (unsigned short*)p;  p += 8 * 64 * 8 * 2;
    unsigned short* wpb = (unsigned short*)p;  p += 4 * 64 * 8 * 2;
    float* o1v = (float*)p;  p += 64 * 4;
    float* scv = (float*)p;  p += 64 * 4;
    float* shv = (float*)p;

    // cnt + gcursor cleared in ONE memset (adjacent)
    hipMemsetAsync(cnt, 0, (size_t)NVOX_ * 4 + 16, stream);

    k_hist<<<(NPT_ + 255) / 256, 256, 0, stream>>>(indices, paddings, cnt);

    k_offsets<<<513, 256, 0, stream>>>(cnt, off, cur, rid, gcur,
        cw, w_pn, g1, b1, m1, v1, g2, b2, m2, v2,
        cwb, wpb, o1v, scv, shv);

    k_z<<<3125, 256, 0, stream>>>(feat, indices, paddings, wpb, cur, zs);

    k_redconv<<<8192, 256, 0, stream>>>(zs, cnt, off, rid, o1v, cwb, scv, shv, grid_c);

    // NPT_/32 = 6250 waves -> 1563 blocks (last 2 waves idle)
    k_gather32<<<1563, 256, 0, stream>>>(grid_c, rid, vxyz, shv, (float*)d_out);
}